// Round 2
// baseline (344.519 us; speedup 1.0000x reference)
//
#include <hip/hip_runtime.h>
#include <hip/hip_bf16.h>

#define HEADS 12
#define HD 64
#define DIM 768
#define SEQ 1024
#define NTOK 8192      // B*N = 8*1024
#define TRIPLE 2304    // 3*DIM
#define BHTOT 96       // B*HEADS

typedef __attribute__((ext_vector_type(8))) short bf16x8;
typedef __attribute__((ext_vector_type(4))) float f32x4;

#define MFMA_B16(a, b, c) __builtin_amdgcn_mfma_f32_16x16x32_bf16((a), (b), (c), 0, 0, 0)

// exact RNE float->bf16 (all our values are small exact integers anyway)
__device__ __forceinline__ unsigned short f2bf(float f) {
  unsigned int u = __float_as_uint(f);
  unsigned int r = (u + 0x7fffu + ((u >> 16) & 1u)) >> 16;
  return (unsigned short)r;
}
__device__ __forceinline__ float qclamp(float v, float lo, float hi) {
  return fminf(fmaxf(v, lo), hi);
}

// ---------------- scalar prep: all actq alphas/zps collapse to means ----------------
__device__ float block_mean(const float* p, int n, int rnd, float* red) {
  int t = threadIdx.x;
  float s = 0.f;
  for (int i = t; i < n; i += 256) { float v = p[i]; s += rnd ? rintf(v) : v; }
  red[t] = s;
  __syncthreads();
  for (int o = 128; o > 0; o >>= 1) { if (t < o) red[t] += red[t + o]; __syncthreads(); }
  float m = red[0] / (float)n;
  __syncthreads();
  return m;
}

__global__ __launch_bounds__(256) void k_prep(
    const float* qaa, const float* qzp, const float* qa, const float* qz,
    const float* ka, const float* kz, const float* va, const float* vz,
    const float* ata, const float* atz, const float* pa, const float* pz,
    float* sc) {
  __shared__ float red[256];
  float r0 = block_mean(qaa, 768, 0, red);
  float r1 = block_mean(qzp, 768, 1, red);
  float r2 = block_mean(qa, 12, 0, red);
  float r3 = block_mean(qz, 12, 1, red);
  float r4 = block_mean(ka, 12, 0, red);
  float r5 = block_mean(kz, 12, 1, red);
  float r6 = block_mean(va, 12, 0, red);
  float r7 = block_mean(vz, 12, 1, red);
  float r8 = block_mean(ata, 12, 0, red);
  float r9 = block_mean(atz, 12, 1, red);
  float r10 = block_mean(pa, 768, 0, red);
  float r11 = block_mean(pz, 768, 1, red);
  if (threadIdx.x == 0) {
    sc[0] = r0; sc[1] = r1; sc[2] = r2; sc[3] = r3; sc[4] = r4; sc[5] = r5;
    sc[6] = r6; sc[7] = r7; sc[8] = r8; sc[9] = r9; sc[10] = r10; sc[11] = r11;
  }
}

// ---------------- activation quantize: xq_int = rint(clip(x/a+z,-8,7)) - z ----------------
__global__ __launch_bounds__(256) void k_quant_act(
    const float* __restrict__ x, unsigned short* __restrict__ xq,
    const float* __restrict__ sc, int n) {
  int i = (blockIdx.x * 256 + threadIdx.x) * 4;
  if (i >= n) return;
  float a = sc[0], z = sc[1];
  float4 v = *(const float4*)(x + i);
  ushort4 o;
  o.x = f2bf(rintf(qclamp(v.x / a + z, -8.f, 7.f)) - z);
  o.y = f2bf(rintf(qclamp(v.y / a + z, -8.f, 7.f)) - z);
  o.z = f2bf(rintf(qclamp(v.z / a + z, -8.f, 7.f)) - z);
  o.w = f2bf(rintf(qclamp(v.w / a + z, -8.f, 7.f)) - z);
  *(ushort4*)(xq + i) = o;
}

// ---------------- weight quantize (per-out-row alpha): wq_int = rint(clip(w/a[o],-8,7)) ----------------
__global__ __launch_bounds__(256) void k_quant_w(
    const float* __restrict__ w, const float* __restrict__ alpha,
    unsigned short* __restrict__ wq, int n, int K) {
  int i = (blockIdx.x * 256 + threadIdx.x) * 4;
  if (i >= n) return;
  float a = alpha[i / K];
  float4 v = *(const float4*)(w + i);
  ushort4 o;
  o.x = f2bf(rintf(qclamp(v.x / a, -8.f, 7.f)));
  o.y = f2bf(rintf(qclamp(v.y / a, -8.f, 7.f)));
  o.z = f2bf(rintf(qclamp(v.z / a, -8.f, 7.f)));
  o.w = f2bf(rintf(qclamp(v.w / a, -8.f, 7.f)));
  *(ushort4*)(wq + i) = o;
}

// ---------------- bf16-integer MFMA GEMM: out[m,o] = sact*colscale[o]*sum_k A[m,k]*B[o,k] (+bias) ----------------
// 128x128 tile, BK=64, 4 waves (each 64x64 quadrant). Padded LDS (stride 72) -> 2-way-free banks.
__global__ __launch_bounds__(256) void k_gemm(
    const unsigned short* __restrict__ A, const unsigned short* __restrict__ Bw,
    float* __restrict__ out, const float* __restrict__ colscale,
    const float* __restrict__ bias, const float* __restrict__ sc, int sact_idx,
    int M, int Nt, int K) {
  __shared__ unsigned short As[128][72];
  __shared__ unsigned short Bs[128][72];
  const int t = threadIdx.x;
  const int brow = blockIdx.x * 128, bcol = blockIdx.y * 128;
  const int w = t >> 6, l = t & 63;
  const int lr = l & 15, lg = l >> 4;
  const int wr = (w >> 1) * 64, wc = (w & 1) * 64;
  const int sr = t >> 1, sc0 = (t & 1) * 32;
  f32x4 acc[4][4] = {};
  for (int kt = 0; kt < K; kt += 64) {
    const uint4* ga = (const uint4*)(A + (size_t)(brow + sr) * K + kt + sc0);
    uint4 a0 = ga[0], a1 = ga[1], a2 = ga[2], a3 = ga[3];
    const uint4* gb = (const uint4*)(Bw + (size_t)(bcol + sr) * K + kt + sc0);
    uint4 b0 = gb[0], b1 = gb[1], b2 = gb[2], b3 = gb[3];
    __syncthreads();
    { uint4* d = (uint4*)&As[sr][sc0]; d[0] = a0; d[1] = a1; d[2] = a2; d[3] = a3; }
    { uint4* d = (uint4*)&Bs[sr][sc0]; d[0] = b0; d[1] = b1; d[2] = b2; d[3] = b3; }
    __syncthreads();
#pragma unroll
    for (int ks = 0; ks < 2; ++ks) {
      bf16x8 af[4], bfr[4];
#pragma unroll
      for (int i = 0; i < 4; ++i) {
        af[i] = *(const bf16x8*)&As[wr + i * 16 + lr][ks * 32 + lg * 8];
        bfr[i] = *(const bf16x8*)&Bs[wc + i * 16 + lr][ks * 32 + lg * 8];
      }
#pragma unroll
      for (int i = 0; i < 4; ++i)
#pragma unroll
        for (int j = 0; j < 4; ++j)
          acc[i][j] = MFMA_B16(af[i], bfr[j], acc[i][j]);
    }
  }
  const float sact = sc[sact_idx];
#pragma unroll
  for (int j = 0; j < 4; ++j) {
    const int col = bcol + wc + j * 16 + lr;
    const float s = sact * colscale[col];
    const float bb = bias ? bias[col] : 0.f;
#pragma unroll
    for (int i = 0; i < 4; ++i) {
      const int row0 = brow + wr + i * 16 + lg * 4;
#pragma unroll
      for (int r = 0; r < 4; ++r)
        out[(size_t)(row0 + r) * Nt + col] = acc[i][j][r] * s + bb;
    }
  }
}

// ---------------- stage C: split qkv, LN(q,k), quantize q/k/v; v written transposed [bh][d][n] ----------------
__global__ __launch_bounds__(256) void k_stagec(
    const float* __restrict__ qkv,
    const float* __restrict__ qg, const float* __restrict__ qb,
    const float* __restrict__ kg, const float* __restrict__ kb,
    const float* __restrict__ sc,
    unsigned short* __restrict__ q2b, unsigned short* __restrict__ k2b,
    unsigned short* __restrict__ v2tb) {
  const int gid = blockIdx.x * 256 + threadIdx.x;
  const int n_ = gid & (SEQ - 1);
  const int bh = gid >> 10;
  const int b_ = bh / HEADS, h_ = bh % HEADS;
  const float* base = qkv + (size_t)(b_ * SEQ + n_) * TRIPLE + h_ * HD;
  float x[HD];
  // ---- Q: LN + quant
  {
#pragma unroll
    for (int d4 = 0; d4 < 16; ++d4) {
      float4 v = *(const float4*)(base + d4 * 4);
      x[d4 * 4] = v.x; x[d4 * 4 + 1] = v.y; x[d4 * 4 + 2] = v.z; x[d4 * 4 + 3] = v.w;
    }
    float m = 0.f;
#pragma unroll
    for (int d = 0; d < HD; ++d) m += x[d];
    m *= (1.f / HD);
    float var = 0.f;
#pragma unroll
    for (int d = 0; d < HD; ++d) { float dd = x[d] - m; var += dd * dd; }
    var *= (1.f / HD);
    float inv = 1.0f / sqrtf(var + 1e-5f);
    float aq = sc[2], zq = sc[3];
    unsigned short* qp = q2b + (size_t)bh * (SEQ * HD) + n_ * HD;
#pragma unroll
    for (int d4 = 0; d4 < 16; ++d4) {
      ushort4 o; float yv;
      yv = (x[d4*4+0] - m) * inv * qg[d4*4+0] + qb[d4*4+0]; o.x = f2bf(rintf(qclamp(yv / aq + zq, -8.f, 7.f)) - zq);
      yv = (x[d4*4+1] - m) * inv * qg[d4*4+1] + qb[d4*4+1]; o.y = f2bf(rintf(qclamp(yv / aq + zq, -8.f, 7.f)) - zq);
      yv = (x[d4*4+2] - m) * inv * qg[d4*4+2] + qb[d4*4+2]; o.z = f2bf(rintf(qclamp(yv / aq + zq, -8.f, 7.f)) - zq);
      yv = (x[d4*4+3] - m) * inv * qg[d4*4+3] + qb[d4*4+3]; o.w = f2bf(rintf(qclamp(yv / aq + zq, -8.f, 7.f)) - zq);
      *(ushort4*)(qp + d4 * 4) = o;
    }
  }
  // ---- K: LN + quant
  {
    const float* kbase = base + DIM;
#pragma unroll
    for (int d4 = 0; d4 < 16; ++d4) {
      float4 v = *(const float4*)(kbase + d4 * 4);
      x[d4 * 4] = v.x; x[d4 * 4 + 1] = v.y; x[d4 * 4 + 2] = v.z; x[d4 * 4 + 3] = v.w;
    }
    float m = 0.f;
#pragma unroll
    for (int d = 0; d < HD; ++d) m += x[d];
    m *= (1.f / HD);
    float var = 0.f;
#pragma unroll
    for (int d = 0; d < HD; ++d) { float dd = x[d] - m; var += dd * dd; }
    var *= (1.f / HD);
    float inv = 1.0f / sqrtf(var + 1e-5f);
    float ak = sc[4], zk = sc[5];
    unsigned short* kp = k2b + (size_t)bh * (SEQ * HD) + n_ * HD;
#pragma unroll
    for (int d4 = 0; d4 < 16; ++d4) {
      ushort4 o; float yv;
      yv = (x[d4*4+0] - m) * inv * kg[d4*4+0] + kb[d4*4+0]; o.x = f2bf(rintf(qclamp(yv / ak + zk, -8.f, 7.f)) - zk);
      yv = (x[d4*4+1] - m) * inv * kg[d4*4+1] + kb[d4*4+1]; o.y = f2bf(rintf(qclamp(yv / ak + zk, -8.f, 7.f)) - zk);
      yv = (x[d4*4+2] - m) * inv * kg[d4*4+2] + kb[d4*4+2]; o.z = f2bf(rintf(qclamp(yv / ak + zk, -8.f, 7.f)) - zk);
      yv = (x[d4*4+3] - m) * inv * kg[d4*4+3] + kb[d4*4+3]; o.w = f2bf(rintf(qclamp(yv / ak + zk, -8.f, 7.f)) - zk);
      *(ushort4*)(kp + d4 * 4) = o;
    }
  }
  // ---- V: quant only, store transposed [d][n] (coalesced across lanes per d)
  {
    const float* vbase = base + 2 * DIM;
#pragma unroll
    for (int d4 = 0; d4 < 16; ++d4) {
      float4 v = *(const float4*)(vbase + d4 * 4);
      x[d4 * 4] = v.x; x[d4 * 4 + 1] = v.y; x[d4 * 4 + 2] = v.z; x[d4 * 4 + 3] = v.w;
    }
    float av_ = sc[6], zv = sc[7];
    unsigned short* vp = v2tb + (size_t)bh * (SEQ * HD) + n_;
#pragma unroll
    for (int d = 0; d < HD; ++d)
      vp[(size_t)d * SEQ] = f2bf(rintf(qclamp(x[d] / av_ + zv, -8.f, 7.f)) - zv);
  }
}

// ---------------- fused attention: per (b,h, 128 q rows); 4 waves x 32 q rows ----------------
// pass1: QK^T (bf16 int MFMA) + online (m,l). pass2: QK^T again, quantize P -> LDS, PV MFMA.
// Epilogue fuses proj-input quantization -> x1q bf16-int [NTOK][DIM].
__global__ __launch_bounds__(256) void k_attn(
    const unsigned short* __restrict__ q2b, const unsigned short* __restrict__ k2b,
    const unsigned short* __restrict__ v2tb, unsigned short* __restrict__ x1q,
    const float* __restrict__ sc) {
  __shared__ unsigned short Ks[128][72];     // k rows x d (padded)
  __shared__ unsigned short Vs[64][136];     // d x k-tile (padded)
  __shared__ unsigned short Ps[4][32][136];  // per-wave quantized P
  const int t = threadIdx.x;
  const int w = t >> 6, l = t & 63;
  const int lr = l & 15, lg = l >> 4;
  const int bh = blockIdx.x >> 3, qc = blockIdx.x & 7;
  const unsigned short* Qg = q2b + (size_t)bh * (SEQ * HD);
  const unsigned short* Kg = k2b + (size_t)bh * (SEQ * HD);
  const unsigned short* Vg = v2tb + (size_t)bh * (SEQ * HD);
  const float aq = sc[2], ak = sc[4], av_ = sc[6], aa = sc[8], za = sc[9];
  const float ap = sc[10], zpp = sc[11];
  const float sqk = aq * ak * 0.125f;  // SCALE = 64^-0.5
  const float spv = aa * av_;
  const int qr0 = qc * 128 + w * 32;

  bf16x8 qf[2][2];
#pragma unroll
  for (int rt = 0; rt < 2; ++rt)
#pragma unroll
    for (int ks = 0; ks < 2; ++ks)
      qf[rt][ks] = *(const bf16x8*)(Qg + (size_t)(qr0 + rt * 16 + lr) * HD + ks * 32 + lg * 8);

  float mrow[2][4], lrow[2][4];
#pragma unroll
  for (int rt = 0; rt < 2; ++rt)
#pragma unroll
    for (int r = 0; r < 4; ++r) { mrow[rt][r] = -3.0e38f; lrow[rt][r] = 0.f; }

  const int sr = t >> 1, sc0 = (t & 1) * 32;
  const int vr = t >> 2, vc0 = (t & 3) * 32;

  // ---- pass 1: stats
  for (int kt = 0; kt < SEQ; kt += 128) {
    const uint4* g = (const uint4*)(Kg + (size_t)(kt + sr) * HD + sc0);
    uint4 u0 = g[0], u1 = g[1], u2 = g[2], u3 = g[3];
    __syncthreads();
    { uint4* d = (uint4*)&Ks[sr][sc0]; d[0] = u0; d[1] = u1; d[2] = u2; d[3] = u3; }
    __syncthreads();
#pragma unroll
    for (int ct = 0; ct < 8; ++ct) {
      const int kl = ct * 16 + lr;
      bf16x8 kf0 = *(const bf16x8*)&Ks[kl][lg * 8];
      bf16x8 kf1 = *(const bf16x8*)&Ks[kl][32 + lg * 8];
#pragma unroll
      for (int rt = 0; rt < 2; ++rt) {
        f32x4 s4 = {0.f, 0.f, 0.f, 0.f};
        s4 = MFMA_B16(qf[rt][0], kf0, s4);
        s4 = MFMA_B16(qf[rt][1], kf1, s4);
#pragma unroll
        for (int r = 0; r < 4; ++r) {
          float s = s4[r] * sqk;
          float mo = mrow[rt][r];
          float mn = fmaxf(mo, s);
          lrow[rt][r] = lrow[rt][r] * __expf(mo - mn) + __expf(s - mn);
          mrow[rt][r] = mn;
        }
      }
    }
  }
  // reduce (m,l) across the 16 lanes sharing rows
#pragma unroll
  for (int off = 1; off < 16; off <<= 1) {
#pragma unroll
    for (int rt = 0; rt < 2; ++rt)
#pragma unroll
      for (int r = 0; r < 4; ++r) {
        float mo = __shfl_xor(mrow[rt][r], off);
        float lo = __shfl_xor(lrow[rt][r], off);
        float mn = fmaxf(mrow[rt][r], mo);
        lrow[rt][r] = lrow[rt][r] * __expf(mrow[rt][r] - mn) + lo * __expf(mo - mn);
        mrow[rt][r] = mn;
      }
  }
  float pinv[2][4];
#pragma unroll
  for (int rt = 0; rt < 2; ++rt)
#pragma unroll
    for (int r = 0; r < 4; ++r) pinv[rt][r] = 1.0f / (lrow[rt][r] * aa);

  // ---- pass 2: quantize P + PV
  f32x4 oacc[2][4] = {};
  for (int kt = 0; kt < SEQ; kt += 128) {
    const uint4* gk = (const uint4*)(Kg + (size_t)(kt + sr) * HD + sc0);
    uint4 u0 = gk[0], u1 = gk[1], u2 = gk[2], u3 = gk[3];
    const uint4* gv = (const uint4*)(Vg + (size_t)vr * SEQ + kt + vc0);
    uint4 w0 = gv[0], w1 = gv[1], w2 = gv[2], w3 = gv[3];
    __syncthreads();
    { uint4* d = (uint4*)&Ks[sr][sc0]; d[0] = u0; d[1] = u1; d[2] = u2; d[3] = u3; }
    { uint4* d = (uint4*)&Vs[vr][vc0]; d[0] = w0; d[1] = w1; d[2] = w2; d[3] = w3; }
    __syncthreads();
#pragma unroll
    for (int ct = 0; ct < 8; ++ct) {
      const int kl = ct * 16 + lr;
      bf16x8 kf0 = *(const bf16x8*)&Ks[kl][lg * 8];
      bf16x8 kf1 = *(const bf16x8*)&Ks[kl][32 + lg * 8];
#pragma unroll
      for (int rt = 0; rt < 2; ++rt) {
        f32x4 s4 = {0.f, 0.f, 0.f, 0.f};
        s4 = MFMA_B16(qf[rt][0], kf0, s4);
        s4 = MFMA_B16(qf[rt][1], kf1, s4);
#pragma unroll
        for (int r = 0; r < 4; ++r) {
          float s = s4[r] * sqk;
          float p = __expf(s - mrow[rt][r]) * pinv[rt][r] + za;
          float qv = rintf(qclamp(p, 0.f, 15.f)) - za;
          Ps[w][rt * 16 + lg * 4 + r][ct * 16 + lr] = f2bf(qv);
        }
      }
    }
    __syncthreads();
#pragma unroll
    for (int ks2 = 0; ks2 < 4; ++ks2) {
      bf16x8 vf[4], pf[2];
#pragma unroll
      for (int dt = 0; dt < 4; ++dt)
        vf[dt] = *(const bf16x8*)&Vs[dt * 16 + lr][ks2 * 32 + lg * 8];
#pragma unroll
      for (int rt = 0; rt < 2; ++rt)
        pf[rt] = *(const bf16x8*)&Ps[w][rt * 16 + lr][ks2 * 32 + lg * 8];
#pragma unroll
      for (int rt = 0; rt < 2; ++rt)
#pragma unroll
        for (int dt = 0; dt < 4; ++dt)
          oacc[rt][dt] = MFMA_B16(pf[rt], vf[dt], oacc[rt][dt]);
    }
  }
  // ---- epilogue: x1 = spv*acc, fuse proj-input quantization
  const int b_ = bh / HEADS, h_ = bh % HEADS;
#pragma unroll
  for (int rt = 0; rt < 2; ++rt)
#pragma unroll
    for (int dt = 0; dt < 4; ++dt) {
      const int col = h_ * HD + dt * 16 + lr;
#pragma unroll
      for (int r = 0; r < 4; ++r) {
        const int qrow = qr0 + rt * 16 + lg * 4 + r;
        float x1v = oacc[rt][dt][r] * spv;
        float xv = rintf(qclamp(x1v / ap + zpp, -8.f, 7.f)) - zpp;
        x1q[(size_t)(b_ * SEQ + qrow) * DIM + col] = f2bf(xv);
      }
    }
}

extern "C" void kernel_launch(void* const* d_in, const int* in_sizes, int n_in,
                              void* d_out, int out_size, void* d_ws, size_t ws_size,
                              hipStream_t stream) {
  const float* x0      = (const float*)d_in[0];
  const float* qkvw    = (const float*)d_in[1];
  const float* qkv_aw  = (const float*)d_in[2];
  const float* qkv_aa  = (const float*)d_in[3];
  const float* qkv_azp = (const float*)d_in[4];
  const float* nqg     = (const float*)d_in[5];
  const float* nqb     = (const float*)d_in[6];
  const float* nkg     = (const float*)d_in[7];
  const float* nkb     = (const float*)d_in[8];
  const float* q_a     = (const float*)d_in[9];
  const float* q_z     = (const float*)d_in[10];
  const float* k_a     = (const float*)d_in[11];
  const float* k_z     = (const float*)d_in[12];
  const float* v_a     = (const float*)d_in[13];
  const float* v_z     = (const float*)d_in[14];
  const float* at_a    = (const float*)d_in[15];
  const float* at_z    = (const float*)d_in[16];
  const float* pw      = (const float*)d_in[17];
  const float* pb      = (const float*)d_in[18];
  const float* p_aw    = (const float*)d_in[19];
  const float* p_aa    = (const float*)d_in[20];
  const float* p_azp   = (const float*)d_in[21];
  float* out = (float*)d_out;

  char* ws = (char*)d_ws;
  size_t off = 0;
  float* scal = (float*)(ws); off = 256;
  unsigned short* x0q  = (unsigned short*)(ws + off); off += (size_t)NTOK * DIM * 2;
  unsigned short* qwq  = (unsigned short*)(ws + off); off += (size_t)TRIPLE * DIM * 2;
  unsigned short* pwq  = (unsigned short*)(ws + off); off += (size_t)DIM * DIM * 2;
  float* qkvf          = (float*)(ws + off);          off += (size_t)NTOK * TRIPLE * 4;
  unsigned short* q2b  = (unsigned short*)(ws + off); off += (size_t)BHTOT * SEQ * HD * 2;
  unsigned short* k2b  = (unsigned short*)(ws + off); off += (size_t)BHTOT * SEQ * HD * 2;
  unsigned short* v2tb = (unsigned short*)(ws + off); off += (size_t)BHTOT * SEQ * HD * 2;
  unsigned short* x1q  = (unsigned short*)(ws + off); off += (size_t)NTOK * DIM * 2;

  k_prep<<<1, 256, 0, stream>>>(qkv_aa, qkv_azp, q_a, q_z, k_a, k_z, v_a, v_z,
                                at_a, at_z, p_aa, p_azp, scal);
  k_quant_act<<<(NTOK * DIM) / 1024, 256, 0, stream>>>(x0, x0q, scal, NTOK * DIM);
  k_quant_w<<<(TRIPLE * DIM) / 1024, 256, 0, stream>>>(qkvw, qkv_aw, qwq, TRIPLE * DIM, DIM);
  k_quant_w<<<(DIM * DIM) / 1024, 256, 0, stream>>>(pw, p_aw, pwq, DIM * DIM, DIM);
  k_gemm<<<dim3(NTOK / 128, TRIPLE / 128), 256, 0, stream>>>(
      x0q, qwq, qkvf, qkv_aw, nullptr, scal, 0, NTOK, TRIPLE, DIM);
  k_stagec<<<(BHTOT * SEQ) / 256, 256, 0, stream>>>(qkvf, nqg, nqb, nkg, nkb, scal,
                                                    q2b, k2b, v2tb);
  k_attn<<<BHTOT * 8, 256, 0, stream>>>(q2b, k2b, v2tb, x1q, scal);
  k_gemm<<<dim3(NTOK / 128, DIM / 128), 256, 0, stream>>>(
      x1q, pwq, out, p_aw, pb, scal, 10, NTOK, DIM, DIM);
}